// Round 1
// baseline (389.727 us; speedup 1.0000x reference)
//
#include <hip/hip_runtime.h>
#include <math.h>

#define BB     8
#define NN     1024
#define EE     256
#define DMODEL 64
#define HH     4
#define DHH    16

// workspace layout (float offsets)
#define WS_Q    0           // [B][H][N][16]   = 524288
#define WS_K    524288      // [B][H][N][16]   = 524288
#define WS_EQ   1048576     // [4][B][H][E][16] each 131072 (eq, ek, ceq, cek)
#define WS_GQ   1572864     // [2][B][H][N][16] = 1048576
#define WS_GKT  2621440     // [2][B][H][16][N] = 1048576
// total 3670016 floats = 14680064 bytes

// ---------------------------------------------------------------------------
// K1: fused embedding + Q/K projection.  block = 256 = 4 positions x 64 dims
// ---------------------------------------------------------------------------
__global__ __launch_bounds__(256) void qk_kernel(
    const float* __restrict__ x, const float* __restrict__ W_emb,
    const float* __restrict__ b_emb, const float* __restrict__ W_q,
    const float* __restrict__ b_q, const float* __restrict__ W_k,
    const float* __restrict__ b_k, float* __restrict__ ws) {
  __shared__ float semb[4][DMODEL];
  const int tid = threadIdx.x;
  const int p = tid >> 6, d = tid & 63;
  const int pos = blockIdx.x * 4 + p;  // b*N + n
  const float x0 = x[pos * 2 + 0];
  const float x1 = x[pos * 2 + 1];
  semb[p][d] = fmaf(x0, W_emb[d], fmaf(x1, W_emb[DMODEL + d], b_emb[d]));
  __syncthreads();
  float accq = b_q[d], acck = b_k[d];
#pragma unroll 8
  for (int e = 0; e < DMODEL; ++e) {
    const float ev = semb[p][e];
    accq = fmaf(ev, W_q[e * DMODEL + d], accq);
    acck = fmaf(ev, W_k[e * DMODEL + d], acck);
  }
  const int b = pos >> 10, n = pos & (NN - 1);
  const int h = d >> 4, c = d & 15;
  const int oidx = ((b * HH + h) * NN + n) * DHH + c;
  ws[WS_Q + oidx] = accq;
  ws[WS_K + oidx] = acck;
}

// ---------------------------------------------------------------------------
// K2: edge projections eq/ek/ceq/cek.  t uniform per block (32 blocks/tensor)
// ---------------------------------------------------------------------------
__global__ __launch_bounds__(256) void edge_proj_kernel(
    const float* __restrict__ edge, const float* __restrict__ C_edge,
    const float* __restrict__ W_eq, const float* __restrict__ b_eq,
    const float* __restrict__ W_ek, const float* __restrict__ b_ek,
    const float* __restrict__ W_ceq, const float* __restrict__ b_ceq,
    const float* __restrict__ W_cek, const float* __restrict__ b_cek,
    float* __restrict__ ws) {
  const int t = blockIdx.x >> 5;                       // 0..3
  const int row = ((blockIdx.x & 31) << 8) + threadIdx.x;  // (b*H+h)*E+e
  const float* __restrict__ src = (t < 2) ? edge : C_edge;
  const float* __restrict__ W =
      (t == 0) ? W_eq : (t == 1) ? W_ek : (t == 2) ? W_ceq : W_cek;
  const float* __restrict__ bias =
      (t == 0) ? b_eq : (t == 1) ? b_ek : (t == 2) ? b_ceq : b_cek;
  float in[16];
  const float4* s4 = (const float4*)(src + row * 16);
#pragma unroll
  for (int i = 0; i < 4; ++i) {
    const float4 v = s4[i];
    in[4 * i + 0] = v.x; in[4 * i + 1] = v.y;
    in[4 * i + 2] = v.z; in[4 * i + 3] = v.w;
  }
  float outv[16];
#pragma unroll
  for (int c = 0; c < 16; ++c) outv[c] = bias[c];
#pragma unroll
  for (int cp = 0; cp < 16; ++cp) {
    const float iv = in[cp];
#pragma unroll
    for (int c = 0; c < 16; ++c) outv[c] = fmaf(iv, W[cp * 16 + c], outv[c]);
  }
  float4* o4 = (float4*)(ws + WS_EQ + t * 131072 + row * 16);
#pragma unroll
  for (int i = 0; i < 4; ++i)
    o4[i] = make_float4(outv[4 * i + 0], outv[4 * i + 1], outv[4 * i + 2],
                        outv[4 * i + 3]);
}

// ---------------------------------------------------------------------------
// K3: gq = q + (G^T @ eq)/div ; gk^T = (k + (G^T @ ek)/div)^T, div fused.
// blockIdx = mat*8 + sub;  mat=(br*8+b)*4+h (uniform -> scalar eq/ek loads)
// sub = nchunk(2b) | chalf(1b); each thread: one n, 8 of 16 channels, both q&k
// ---------------------------------------------------------------------------
__global__ __launch_bounds__(256) void gqgk_kernel(
    const float* __restrict__ G, const float* __restrict__ C_G,
    float* __restrict__ ws) {
  const int sub = blockIdx.x & 7;
  const int mat = blockIdx.x >> 3;  // (br*8+b)*4+h
  const int h = mat & 3;
  const int b = (mat >> 2) & 7;
  const int br = mat >> 5;
  const int nchunk = sub >> 1;
  const int c0 = (sub & 1) * 8;
  const int n = (nchunk << 8) + threadIdx.x;
  const float* __restrict__ Gm = br ? C_G : G;
  const float* __restrict__ eqp =
      ws + WS_EQ + (br * 2 + 0) * 131072 + (b * HH + h) * EE * 16 + c0;
  const float* __restrict__ ekp =
      ws + WS_EQ + (br * 2 + 1) * 131072 + (b * HH + h) * EE * 16 + c0;
  const float* __restrict__ gcol = Gm + b * EE * NN + n;
  float accq[8] = {0.f, 0.f, 0.f, 0.f, 0.f, 0.f, 0.f, 0.f};
  float acck[8] = {0.f, 0.f, 0.f, 0.f, 0.f, 0.f, 0.f, 0.f};
  float div = 0.f;
#pragma unroll 4
  for (int e = 0; e < EE; ++e) {
    const float g = gcol[e * NN];
    div += g;
#pragma unroll
    for (int c = 0; c < 8; ++c) {
      accq[c] = fmaf(g, eqp[e * 16 + c], accq[c]);
      acck[c] = fmaf(g, ekp[e * 16 + c], acck[c]);
    }
  }
  const float inv = 1.0f / div;
  const int qidx = ((b * HH + h) * NN + n) * 16 + c0;
  const float* __restrict__ qrow = ws + WS_Q + qidx;
  const float* __restrict__ krow = ws + WS_K + qidx;
  float* __restrict__ gq = ws + WS_GQ + (mat * NN + n) * 16 + c0;
  float* __restrict__ gkT = ws + WS_GKT + mat * 16 * NN + n;
#pragma unroll
  for (int c = 0; c < 8; ++c) {
    gq[c] = qrow[c] + accq[c] * inv;
    gkT[(c0 + c) * NN] = krow[c] + acck[c] * inv;
  }
}

// ---------------------------------------------------------------------------
// K4 (the heavy one): scores + softmax + write.
// block = 256 thr = 4 waves; block owns (branch,b,h, 32-row tile);
// wave owns 8 rows x 1024 cols; lane owns cols {lane + 64*t, t=0..15}.
// gk^T staged in LDS [16][1024] -> all reads 64-lane contiguous (no conflicts)
// ---------------------------------------------------------------------------
__global__ __launch_bounds__(256, 2) void attn_kernel(
    const float* __restrict__ ws, float* __restrict__ out) {
  __shared__ float skT[16 * NN];  // 64 KB
  const int idx = blockIdx.x;
  const int rb = idx & 31;
  const int mat = idx >> 5;  // (br*8+b)*4+h == output matrix index
  const float* __restrict__ gkTp = ws + WS_GKT + mat * 16 * NN;
  const float* __restrict__ gqp = ws + WS_GQ + (mat * NN + rb * 32) * 16;
  const int tid = threadIdx.x;
  const float4* __restrict__ src4 = (const float4*)gkTp;
  float4* dst4 = (float4*)skT;
#pragma unroll
  for (int i = 0; i < 16; ++i) dst4[tid + 256 * i] = src4[tid + 256 * i];
  __syncthreads();
  const int wave = tid >> 6, lane = tid & 63;
  const int r0 = wave * 8;
  float s[8][16];
#pragma unroll
  for (int r = 0; r < 8; ++r)
#pragma unroll
    for (int t = 0; t < 16; ++t) s[r][t] = 0.f;

  for (int c = 0; c < 16; ++c) {
    float gkv[16];
#pragma unroll
    for (int t = 0; t < 16; ++t) gkv[t] = skT[c * NN + lane + 64 * t];
#pragma unroll
    for (int r = 0; r < 8; ++r) {
      const float qv = gqp[(r0 + r) * 16 + c];
#pragma unroll
      for (int t = 0; t < 16; ++t) s[r][t] = fmaf(qv, gkv[t], s[r][t]);
    }
  }

#pragma unroll
  for (int r = 0; r < 8; ++r) {
    float m = s[r][0];
#pragma unroll
    for (int t = 1; t < 16; ++t) m = fmaxf(m, s[r][t]);
#pragma unroll
    for (int off = 32; off; off >>= 1) m = fmaxf(m, __shfl_xor(m, off));
    float sum = 0.f;
#pragma unroll
    for (int t = 0; t < 16; ++t) {
      s[r][t] = __expf((s[r][t] - m) * 0.125f);  // softmax(score/sqrt(64))
      sum += s[r][t];
    }
#pragma unroll
    for (int off = 32; off; off >>= 1) sum += __shfl_xor(sum, off);
    const float inv = 1.0f / sum;
    float* __restrict__ orow =
        out + ((size_t)mat * NN + (size_t)(rb * 32 + r0 + r)) * NN;
#pragma unroll
    for (int t = 0; t < 16; ++t) orow[lane + 64 * t] = s[r][t] * inv;
  }
}

// ---------------------------------------------------------------------------
extern "C" void kernel_launch(void* const* d_in, const int* in_sizes, int n_in,
                              void* d_out, int out_size, void* d_ws,
                              size_t ws_size, hipStream_t stream) {
  const float* x      = (const float*)d_in[0];
  const float* edge   = (const float*)d_in[1];
  const float* C_edge = (const float*)d_in[2];
  const float* G      = (const float*)d_in[3];
  const float* C_G    = (const float*)d_in[4];
  const float* W_emb  = (const float*)d_in[5];
  const float* b_emb  = (const float*)d_in[6];
  const float* W_q    = (const float*)d_in[7];
  const float* b_q    = (const float*)d_in[8];
  const float* W_k    = (const float*)d_in[9];
  const float* b_k    = (const float*)d_in[10];
  const float* W_eq   = (const float*)d_in[11];
  const float* b_eq   = (const float*)d_in[12];
  const float* W_ek   = (const float*)d_in[13];
  const float* b_ek   = (const float*)d_in[14];
  const float* W_ceq  = (const float*)d_in[15];
  const float* b_ceq  = (const float*)d_in[16];
  const float* W_cek  = (const float*)d_in[17];
  const float* b_cek  = (const float*)d_in[18];
  float* ws = (float*)d_ws;
  float* out = (float*)d_out;

  hipLaunchKernelGGL(qk_kernel, dim3(BB * NN / 4), dim3(256), 0, stream, x,
                     W_emb, b_emb, W_q, b_q, W_k, b_k, ws);
  hipLaunchKernelGGL(edge_proj_kernel, dim3(128), dim3(256), 0, stream, edge,
                     C_edge, W_eq, b_eq, W_ek, b_ek, W_ceq, b_ceq, W_cek,
                     b_cek, ws);
  hipLaunchKernelGGL(gqgk_kernel, dim3(512), dim3(256), 0, stream, G, C_G, ws);
  hipLaunchKernelGGL(attn_kernel, dim3(2 * BB * HH * (NN / 32)), dim3(256), 0,
                     stream, ws, out);
}

// Round 2
// 385.404 us; speedup vs baseline: 1.0112x; 1.0112x over previous
//
#include <hip/hip_runtime.h>
#include <math.h>

#define BB     8
#define NN     1024
#define EE     256
#define DMODEL 64
#define HH     4
#define DHH    16

// workspace layout (float offsets)
#define WS_Q    0           // [B][H][N][16]   = 524288
#define WS_K    524288      // [B][H][N][16]   = 524288
#define WS_EQ   1048576     // [4][B][H][E][16] each 131072 (eq, ek, ceq, cek)
#define WS_GQ   1572864     // [2][B][H][N][16] = 1048576
#define WS_GKT  2621440     // [2][B][H][16][N] = 1048576
// total 3670016 floats = 14680064 bytes

// ---------------------------------------------------------------------------
// K1: fused embedding + Q/K projection.  block = 256 = 4 positions x 64 dims
// ---------------------------------------------------------------------------
__global__ __launch_bounds__(256) void qk_kernel(
    const float* __restrict__ x, const float* __restrict__ W_emb,
    const float* __restrict__ b_emb, const float* __restrict__ W_q,
    const float* __restrict__ b_q, const float* __restrict__ W_k,
    const float* __restrict__ b_k, float* __restrict__ ws) {
  __shared__ float semb[4][DMODEL];
  const int tid = threadIdx.x;
  const int p = tid >> 6, d = tid & 63;
  const int pos = blockIdx.x * 4 + p;  // b*N + n
  const float x0 = x[pos * 2 + 0];
  const float x1 = x[pos * 2 + 1];
  semb[p][d] = fmaf(x0, W_emb[d], fmaf(x1, W_emb[DMODEL + d], b_emb[d]));
  __syncthreads();
  float accq = b_q[d], acck = b_k[d];
#pragma unroll 8
  for (int e = 0; e < DMODEL; ++e) {
    const float ev = semb[p][e];
    accq = fmaf(ev, W_q[e * DMODEL + d], accq);
    acck = fmaf(ev, W_k[e * DMODEL + d], acck);
  }
  const int b = pos >> 10, n = pos & (NN - 1);
  const int h = d >> 4, c = d & 15;
  const int oidx = ((b * HH + h) * NN + n) * DHH + c;
  ws[WS_Q + oidx] = accq;
  ws[WS_K + oidx] = acck;
}

// ---------------------------------------------------------------------------
// K2: edge projections eq/ek/ceq/cek.  t uniform per block (32 blocks/tensor)
// ---------------------------------------------------------------------------
__global__ __launch_bounds__(256) void edge_proj_kernel(
    const float* __restrict__ edge, const float* __restrict__ C_edge,
    const float* __restrict__ W_eq, const float* __restrict__ b_eq,
    const float* __restrict__ W_ek, const float* __restrict__ b_ek,
    const float* __restrict__ W_ceq, const float* __restrict__ b_ceq,
    const float* __restrict__ W_cek, const float* __restrict__ b_cek,
    float* __restrict__ ws) {
  const int t = blockIdx.x >> 5;                       // 0..3
  const int row = ((blockIdx.x & 31) << 8) + threadIdx.x;  // (b*H+h)*E+e
  const float* __restrict__ src = (t < 2) ? edge : C_edge;
  const float* __restrict__ W =
      (t == 0) ? W_eq : (t == 1) ? W_ek : (t == 2) ? W_ceq : W_cek;
  const float* __restrict__ bias =
      (t == 0) ? b_eq : (t == 1) ? b_ek : (t == 2) ? b_ceq : b_cek;
  float in[16];
  const float4* s4 = (const float4*)(src + row * 16);
#pragma unroll
  for (int i = 0; i < 4; ++i) {
    const float4 v = s4[i];
    in[4 * i + 0] = v.x; in[4 * i + 1] = v.y;
    in[4 * i + 2] = v.z; in[4 * i + 3] = v.w;
  }
  float outv[16];
#pragma unroll
  for (int c = 0; c < 16; ++c) outv[c] = bias[c];
#pragma unroll
  for (int cp = 0; cp < 16; ++cp) {
    const float iv = in[cp];
#pragma unroll
    for (int c = 0; c < 16; ++c) outv[c] = fmaf(iv, W[cp * 16 + c], outv[c]);
  }
  float4* o4 = (float4*)(ws + WS_EQ + t * 131072 + row * 16);
#pragma unroll
  for (int i = 0; i < 4; ++i)
    o4[i] = make_float4(outv[4 * i + 0], outv[4 * i + 1], outv[4 * i + 2],
                        outv[4 * i + 3]);
}

// ---------------------------------------------------------------------------
// K3: gq = q + (G^T @ eq)/div ; gk^T = (k + (G^T @ ek)/div)^T, div fused.
// blockIdx = mat*8 + sub;  mat=(br*8+b)*4+h (uniform).
// eq/ek channel-half staged in LDS (16 KB) -> inner loop = 1 coalesced G
// load + 16 LDS broadcasts + 17 FMA.  No uniform global loads in the loop.
// ---------------------------------------------------------------------------
__global__ __launch_bounds__(256) void gqgk_kernel(
    const float* __restrict__ G, const float* __restrict__ C_G,
    float* __restrict__ ws) {
  __shared__ float seq[EE * 8];  // 8 KB
  __shared__ float sek[EE * 8];  // 8 KB
  const int sub = blockIdx.x & 7;
  const int mat = blockIdx.x >> 3;  // (br*8+b)*4+h
  const int h = mat & 3;
  const int b = (mat >> 2) & 7;
  const int br = mat >> 5;
  const int nchunk = sub >> 1;
  const int c0 = (sub & 1) * 8;
  const int tid = threadIdx.x;
  const int n = (nchunk << 8) + tid;
  const float* __restrict__ Gm = br ? C_G : G;
  const float* __restrict__ eqbase =
      ws + WS_EQ + (br * 2 + 0) * 131072 + (b * HH + h) * EE * 16 + c0;
  const float* __restrict__ ekbase =
      ws + WS_EQ + (br * 2 + 1) * 131072 + (b * HH + h) * EE * 16 + c0;
  // stage: thread t owns edge-row t (256 rows, 8 channels each)
  {
    const float4* eq4 = (const float4*)(eqbase + tid * 16);
    const float4* ek4 = (const float4*)(ekbase + tid * 16);
    float4* dq = (float4*)(seq + tid * 8);
    float4* dk = (float4*)(sek + tid * 8);
    dq[0] = eq4[0]; dq[1] = eq4[1];
    dk[0] = ek4[0]; dk[1] = ek4[1];
  }
  __syncthreads();
  const float* __restrict__ gcol = Gm + b * EE * NN + n;
  float accq[8] = {0.f, 0.f, 0.f, 0.f, 0.f, 0.f, 0.f, 0.f};
  float acck[8] = {0.f, 0.f, 0.f, 0.f, 0.f, 0.f, 0.f, 0.f};
  float div = 0.f;
#pragma unroll 4
  for (int e = 0; e < EE; ++e) {
    const float g = gcol[e * NN];
    div += g;
#pragma unroll
    for (int c = 0; c < 8; ++c) {
      accq[c] = fmaf(g, seq[e * 8 + c], accq[c]);
      acck[c] = fmaf(g, sek[e * 8 + c], acck[c]);
    }
  }
  const float inv = 1.0f / div;
  const int qidx = ((b * HH + h) * NN + n) * 16 + c0;
  const float* __restrict__ qrow = ws + WS_Q + qidx;
  const float* __restrict__ krow = ws + WS_K + qidx;
  float* __restrict__ gq = ws + WS_GQ + (mat * NN + n) * 16 + c0;
  float* __restrict__ gkT = ws + WS_GKT + mat * 16 * NN + n;
#pragma unroll
  for (int c = 0; c < 8; ++c) {
    gq[c] = qrow[c] + accq[c] * inv;
    gkT[(c0 + c) * NN] = krow[c] + acck[c] * inv;
  }
}

// ---------------------------------------------------------------------------
// K4 (the heavy one): scores + softmax + write.
// block = 256 thr = 4 waves; block owns (branch,b,h, 32-row tile);
// wave owns 8 rows x 1024 cols; lane owns cols {lane + 64*t, t=0..15}.
// gk^T (64 KB) AND the 32x16 gq tile (2 KB) staged in LDS -> the entire
// inner loop touches only LDS (broadcast reads are free; fine lgkmcnt).
// ---------------------------------------------------------------------------
__global__ __launch_bounds__(256, 2) void attn_kernel(
    const float* __restrict__ ws, float* __restrict__ out) {
  __shared__ float skT[16 * NN];  // 64 KB
  __shared__ float sgq[32 * 16];  // 2 KB
  const int idx = blockIdx.x;
  const int rb = idx & 31;
  const int mat = idx >> 5;  // (br*8+b)*4+h == output matrix index
  const float* __restrict__ gkTp = ws + WS_GKT + mat * 16 * NN;
  const float* __restrict__ gqp = ws + WS_GQ + (mat * NN + rb * 32) * 16;
  const int tid = threadIdx.x;
  const float4* __restrict__ src4 = (const float4*)gkTp;
  float4* dst4 = (float4*)skT;
#pragma unroll
  for (int i = 0; i < 16; ++i) dst4[tid + 256 * i] = src4[tid + 256 * i];
  if (tid < 128) ((float4*)sgq)[tid] = ((const float4*)gqp)[tid];
  __syncthreads();
  const int wave = tid >> 6, lane = tid & 63;
  const int r0 = wave * 8;
  float s[8][16];
#pragma unroll
  for (int r = 0; r < 8; ++r)
#pragma unroll
    for (int t = 0; t < 16; ++t) s[r][t] = 0.f;

  for (int c = 0; c < 16; ++c) {
    float gkv[16];
#pragma unroll
    for (int t = 0; t < 16; ++t) gkv[t] = skT[c * NN + lane + 64 * t];
#pragma unroll
    for (int r = 0; r < 8; ++r) {
      const float qv = sgq[(r0 + r) * 16 + c];  // LDS broadcast
#pragma unroll
      for (int t = 0; t < 16; ++t) s[r][t] = fmaf(qv, gkv[t], s[r][t]);
    }
  }

#pragma unroll
  for (int r = 0; r < 8; ++r) {
    float m = s[r][0];
#pragma unroll
    for (int t = 1; t < 16; ++t) m = fmaxf(m, s[r][t]);
#pragma unroll
    for (int off = 32; off; off >>= 1) m = fmaxf(m, __shfl_xor(m, off));
    float sum = 0.f;
#pragma unroll
    for (int t = 0; t < 16; ++t) {
      s[r][t] = __expf((s[r][t] - m) * 0.125f);  // softmax(score/sqrt(64))
      sum += s[r][t];
    }
#pragma unroll
    for (int off = 32; off; off >>= 1) sum += __shfl_xor(sum, off);
    const float inv = 1.0f / sum;
    float* __restrict__ orow =
        out + ((size_t)mat * NN + (size_t)(rb * 32 + r0 + r)) * NN;
#pragma unroll
    for (int t = 0; t < 16; ++t) orow[lane + 64 * t] = s[r][t] * inv;
  }
}

// ---------------------------------------------------------------------------
extern "C" void kernel_launch(void* const* d_in, const int* in_sizes, int n_in,
                              void* d_out, int out_size, void* d_ws,
                              size_t ws_size, hipStream_t stream) {
  const float* x      = (const float*)d_in[0];
  const float* edge   = (const float*)d_in[1];
  const float* C_edge = (const float*)d_in[2];
  const float* G      = (const float*)d_in[3];
  const float* C_G    = (const float*)d_in[4];
  const float* W_emb  = (const float*)d_in[5];
  const float* b_emb  = (const float*)d_in[6];
  const float* W_q    = (const float*)d_in[7];
  const float* b_q    = (const float*)d_in[8];
  const float* W_k    = (const float*)d_in[9];
  const float* b_k    = (const float*)d_in[10];
  const float* W_eq   = (const float*)d_in[11];
  const float* b_eq   = (const float*)d_in[12];
  const float* W_ek   = (const float*)d_in[13];
  const float* b_ek   = (const float*)d_in[14];
  const float* W_ceq  = (const float*)d_in[15];
  const float* b_ceq  = (const float*)d_in[16];
  const float* W_cek  = (const float*)d_in[17];
  const float* b_cek  = (const float*)d_in[18];
  float* ws = (float*)d_ws;
  float* out = (float*)d_out;

  hipLaunchKernelGGL(qk_kernel, dim3(BB * NN / 4), dim3(256), 0, stream, x,
                     W_emb, b_emb, W_q, b_q, W_k, b_k, ws);
  hipLaunchKernelGGL(edge_proj_kernel, dim3(128), dim3(256), 0, stream, edge,
                     C_edge, W_eq, b_eq, W_ek, b_ek, W_ceq, b_ceq, W_cek,
                     b_cek, ws);
  hipLaunchKernelGGL(gqgk_kernel, dim3(512), dim3(256), 0, stream, G, C_G, ws);
  hipLaunchKernelGGL(attn_kernel, dim3(2 * BB * HH * (NN / 32)), dim3(256), 0,
                     stream, ws, out);
}

// Round 3
// 381.153 us; speedup vs baseline: 1.0225x; 1.0112x over previous
//
#include <hip/hip_runtime.h>
#include <math.h>

#define BB     8
#define NN     1024
#define EE     256
#define DMODEL 64
#define HH     4
#define DHH    16

// workspace layout (float offsets)
#define WS_Q    0           // [B][H][N][16]   = 524288
#define WS_K    524288      // [B][H][N][16]   = 524288
#define WS_GQ   1048576     // [2][B][H][N][16] = 1048576
#define WS_GKT  2097152     // [2][B][H][16][N] = 1048576
// total 3145728 floats = 12582912 bytes

// ---------------------------------------------------------------------------
// K1: fused embedding + Q/K projection.  block = 256 = 4 positions x 64 dims
// ---------------------------------------------------------------------------
__global__ __launch_bounds__(256) void qk_kernel(
    const float* __restrict__ x, const float* __restrict__ W_emb,
    const float* __restrict__ b_emb, const float* __restrict__ W_q,
    const float* __restrict__ b_q, const float* __restrict__ W_k,
    const float* __restrict__ b_k, float* __restrict__ ws) {
  __shared__ float semb[4][DMODEL];
  const int tid = threadIdx.x;
  const int p = tid >> 6, d = tid & 63;
  const int pos = blockIdx.x * 4 + p;  // b*N + n
  const float x0 = x[pos * 2 + 0];
  const float x1 = x[pos * 2 + 1];
  semb[p][d] = fmaf(x0, W_emb[d], fmaf(x1, W_emb[DMODEL + d], b_emb[d]));
  __syncthreads();
  float accq = b_q[d], acck = b_k[d];
#pragma unroll 8
  for (int e = 0; e < DMODEL; ++e) {
    const float ev = semb[p][e];
    accq = fmaf(ev, W_q[e * DMODEL + d], accq);
    acck = fmaf(ev, W_k[e * DMODEL + d], acck);
  }
  const int b = pos >> 10, n = pos & (NN - 1);
  const int h = d >> 4, c = d & 15;
  const int oidx = ((b * HH + h) * NN + n) * DHH + c;
  ws[WS_Q + oidx] = accq;
  ws[WS_K + oidx] = acck;
}

// ---------------------------------------------------------------------------
// K2: edge-proj (fused, in LDS) + gq/gk^T with div.
// blockIdx = mat*16 + sub; mat=(br*8+b)*4+h; sub = nchunk(0..3) x cq(0..3).
// Each thread: one n, 4 q-channels + 4 k-channels (cq quarter).
// Staging: thread e computes eq/ek rows for its quarter into LDS (proj
// weights are uniform scalar loads).  Inner loop: 1 coalesced G load +
// broadcast LDS reads + 9 FMA.
// ---------------------------------------------------------------------------
__global__ __launch_bounds__(256) void gqgk_kernel(
    const float* __restrict__ G, const float* __restrict__ C_G,
    const float* __restrict__ edge, const float* __restrict__ C_edge,
    const float* __restrict__ W_eq, const float* __restrict__ b_eq,
    const float* __restrict__ W_ek, const float* __restrict__ b_ek,
    const float* __restrict__ W_ceq, const float* __restrict__ b_ceq,
    const float* __restrict__ W_cek, const float* __restrict__ b_cek,
    float* __restrict__ ws) {
  __shared__ float seq[EE * 4];  // 4 KB
  __shared__ float sek[EE * 4];  // 4 KB
  const int sub = blockIdx.x & 15;
  const int mat = blockIdx.x >> 4;  // (br*8+b)*4+h
  const int h = mat & 3;
  const int b = (mat >> 2) & 7;
  const int br = mat >> 5;
  const int nchunk = sub >> 2;
  const int c0 = (sub & 3) * 4;  // channel quarter
  const int tid = threadIdx.x;
  const int n = (nchunk << 8) + tid;

  const float* __restrict__ Wq = br ? W_ceq : W_eq;
  const float* __restrict__ Wk = br ? W_cek : W_ek;
  const float* __restrict__ bq = br ? b_ceq : b_eq;
  const float* __restrict__ bk = br ? b_cek : b_ek;
  const float* __restrict__ esrc = br ? C_edge : edge;

  // ---- staging: thread tid = edge row e; compute 4 eq + 4 ek channels ----
  {
    float in[16];
    const float4* s4 = (const float4*)(esrc + ((size_t)(b * HH + h) * EE + tid) * 16);
#pragma unroll
    for (int i = 0; i < 4; ++i) {
      const float4 v = s4[i];
      in[4 * i + 0] = v.x; in[4 * i + 1] = v.y;
      in[4 * i + 2] = v.z; in[4 * i + 3] = v.w;
    }
    float aq[4], ak[4];
#pragma unroll
    for (int j = 0; j < 4; ++j) { aq[j] = bq[c0 + j]; ak[j] = bk[c0 + j]; }
#pragma unroll
    for (int cp = 0; cp < 16; ++cp) {
      const float iv = in[cp];
#pragma unroll
      for (int j = 0; j < 4; ++j) {
        aq[j] = fmaf(iv, Wq[cp * 16 + c0 + j], aq[j]);
        ak[j] = fmaf(iv, Wk[cp * 16 + c0 + j], ak[j]);
      }
    }
#pragma unroll
    for (int j = 0; j < 4; ++j) { seq[tid * 4 + j] = aq[j]; sek[tid * 4 + j] = ak[j]; }
  }
  __syncthreads();

  // ---- main loop over E ----
  const float* __restrict__ Gm = br ? C_G : G;
  const float* __restrict__ gcol = Gm + (size_t)b * EE * NN + n;
  float accq[4] = {0.f, 0.f, 0.f, 0.f};
  float acck[4] = {0.f, 0.f, 0.f, 0.f};
  float div = 0.f;
#pragma unroll 8
  for (int e = 0; e < EE; ++e) {
    const float g = gcol[e * NN];
    div += g;
#pragma unroll
    for (int c = 0; c < 4; ++c) {
      accq[c] = fmaf(g, seq[e * 4 + c], accq[c]);
      acck[c] = fmaf(g, sek[e * 4 + c], acck[c]);
    }
  }
  const float inv = 1.0f / div;
  const int qidx = ((b * HH + h) * NN + n) * 16 + c0;
  const float* __restrict__ qrow = ws + WS_Q + qidx;
  const float* __restrict__ krow = ws + WS_K + qidx;
  float* __restrict__ gq = ws + WS_GQ + (mat * NN + n) * 16 + c0;
  float* __restrict__ gkT = ws + WS_GKT + mat * 16 * NN + n;
  float4 qo;
  qo.x = qrow[0] + accq[0] * inv;
  qo.y = qrow[1] + accq[1] * inv;
  qo.z = qrow[2] + accq[2] * inv;
  qo.w = qrow[3] + accq[3] * inv;
  *(float4*)gq = qo;
#pragma unroll
  for (int c = 0; c < 4; ++c)
    gkT[(c0 + c) * NN] = krow[c] + acck[c] * inv;
}

// ---------------------------------------------------------------------------
// K3 (the heavy one): scores + softmax + write.
// block = 1024 thr = 16 waves; block owns (branch,b,h, 64-row tile);
// wave owns 4 rows x 1024 cols; lane owns cols {lane + 64*t, t=0..15}.
// gk^T (64 KB) + 64x16 gq tile (4 KB) in LDS.  16-wave block forces
// VGPR<=128 (s[4][16]=64 fits) -> 4 waves/SIMD occupancy.
// ---------------------------------------------------------------------------
__global__ __launch_bounds__(1024) void attn_kernel(
    const float* __restrict__ ws, float* __restrict__ out) {
  __shared__ float skT[16 * NN];  // 64 KB
  __shared__ float sgq[64 * 16];  // 4 KB
  const int idx = blockIdx.x;
  const int rb = idx & 15;        // 64-row tile index
  const int mat = idx >> 4;       // (br*8+b)*4+h == output matrix index
  const float* __restrict__ gkTp = ws + WS_GKT + mat * 16 * NN;
  const float* __restrict__ gqp = ws + WS_GQ + (mat * NN + rb * 64) * 16;
  const int tid = threadIdx.x;
  const float4* __restrict__ src4 = (const float4*)gkTp;
  float4* dst4 = (float4*)skT;
#pragma unroll
  for (int i = 0; i < 4; ++i) dst4[tid + 1024 * i] = src4[tid + 1024 * i];
  if (tid < 256) ((float4*)sgq)[tid] = ((const float4*)gqp)[tid];
  __syncthreads();
  const int wave = tid >> 6, lane = tid & 63;
  const int r0 = wave * 4;
  float s[4][16];
#pragma unroll
  for (int r = 0; r < 4; ++r)
#pragma unroll
    for (int t = 0; t < 16; ++t) s[r][t] = 0.f;

  for (int c = 0; c < 16; ++c) {
    float gkv[16];
#pragma unroll
    for (int t = 0; t < 16; ++t) gkv[t] = skT[c * NN + lane + 64 * t];
#pragma unroll
    for (int r = 0; r < 4; ++r) {
      const float qv = sgq[(r0 + r) * 16 + c];  // LDS broadcast
#pragma unroll
      for (int t = 0; t < 16; ++t) s[r][t] = fmaf(qv, gkv[t], s[r][t]);
    }
  }

#pragma unroll
  for (int r = 0; r < 4; ++r) {
    float m = s[r][0];
#pragma unroll
    for (int t = 1; t < 16; ++t) m = fmaxf(m, s[r][t]);
#pragma unroll
    for (int off = 32; off; off >>= 1) m = fmaxf(m, __shfl_xor(m, off));
    float sum = 0.f;
#pragma unroll
    for (int t = 0; t < 16; ++t) {
      s[r][t] = __expf((s[r][t] - m) * 0.125f);  // softmax(score/sqrt(64))
      sum += s[r][t];
    }
#pragma unroll
    for (int off = 32; off; off >>= 1) sum += __shfl_xor(sum, off);
    const float inv = 1.0f / sum;
    float* __restrict__ orow =
        out + ((size_t)mat * NN + (size_t)(rb * 64 + r0 + r)) * NN;
#pragma unroll
    for (int t = 0; t < 16; ++t) orow[lane + 64 * t] = s[r][t] * inv;
  }
}

// ---------------------------------------------------------------------------
extern "C" void kernel_launch(void* const* d_in, const int* in_sizes, int n_in,
                              void* d_out, int out_size, void* d_ws,
                              size_t ws_size, hipStream_t stream) {
  const float* x      = (const float*)d_in[0];
  const float* edge   = (const float*)d_in[1];
  const float* C_edge = (const float*)d_in[2];
  const float* G      = (const float*)d_in[3];
  const float* C_G    = (const float*)d_in[4];
  const float* W_emb  = (const float*)d_in[5];
  const float* b_emb  = (const float*)d_in[6];
  const float* W_q    = (const float*)d_in[7];
  const float* b_q    = (const float*)d_in[8];
  const float* W_k    = (const float*)d_in[9];
  const float* b_k    = (const float*)d_in[10];
  const float* W_eq   = (const float*)d_in[11];
  const float* b_eq   = (const float*)d_in[12];
  const float* W_ek   = (const float*)d_in[13];
  const float* b_ek   = (const float*)d_in[14];
  const float* W_ceq  = (const float*)d_in[15];
  const float* b_ceq  = (const float*)d_in[16];
  const float* W_cek  = (const float*)d_in[17];
  const float* b_cek  = (const float*)d_in[18];
  float* ws = (float*)d_ws;
  float* out = (float*)d_out;

  hipLaunchKernelGGL(qk_kernel, dim3(BB * NN / 4), dim3(256), 0, stream, x,
                     W_emb, b_emb, W_q, b_q, W_k, b_k, ws);
  hipLaunchKernelGGL(gqgk_kernel, dim3(2 * BB * HH * 16), dim3(256), 0, stream,
                     G, C_G, edge, C_edge, W_eq, b_eq, W_ek, b_ek, W_ceq,
                     b_ceq, W_cek, b_cek, ws);
  hipLaunchKernelGGL(attn_kernel, dim3(2 * BB * HH * 16), dim3(1024), 0,
                     stream, ws, out);
}